// Round 1
// baseline (1796.805 us; speedup 1.0000x reference)
//
#include <hip/hip_runtime.h>

#define B_DIM 2
#define T_DIM 2048
#define C_DIM 768
#define NH    12
#define HD    64
#define KDIM  768

// ---------------------------------------------------------------------------
// GEMM (B-transposed weights, torch Linear layout):
//   out[m][n] = sum_k A[m][k] * W[n][k]
// A: [M, 768] row-major. W: [N, 768] row-major.
// mode 0: scatter columns into q/k/v [B,H,T,D]   (N = 2304)
// mode 1: dense write out [M, N]                  (N = 768)
// Tiles: 64x64 output per block, BK=16, 256 threads, 4x4 micro-tile.
// ---------------------------------------------------------------------------
__global__ __launch_bounds__(256) void gemm_bt_kernel(
    const float* __restrict__ A, const float* __restrict__ W, int N,
    float* __restrict__ qo, float* __restrict__ ko, float* __restrict__ vo,
    float* __restrict__ dense, int mode)
{
    __shared__ float As[64][20];   // pad 4 -> rows 16B aligned, 2-way banks (free)
    __shared__ float Ws[64][20];

    const int tid = threadIdx.x;
    const int bm  = blockIdx.y * 64;
    const int bn  = blockIdx.x * 64;
    const int ty  = tid >> 4;      // 0..15
    const int tx  = tid & 15;      // 0..15

    const int lr = tid >> 2;         // load row 0..63
    const int lc = (tid & 3) * 4;    // load col 0,4,8,12

    float acc[4][4] = {};

    for (int k0 = 0; k0 < KDIM; k0 += 16) {
        const float4 av = *(const float4*)&A[(size_t)(bm + lr) * KDIM + k0 + lc];
        const float4 wv = *(const float4*)&W[(size_t)(bn + lr) * KDIM + k0 + lc];
        *(float4*)&As[lr][lc] = av;
        *(float4*)&Ws[lr][lc] = wv;
        __syncthreads();
#pragma unroll
        for (int kk = 0; kk < 16; ++kk) {
            float a[4], b[4];
#pragma unroll
            for (int i = 0; i < 4; ++i) a[i] = As[ty * 4 + i][kk];
#pragma unroll
            for (int jj = 0; jj < 4; ++jj) b[jj] = Ws[tx * 4 + jj][kk];
#pragma unroll
            for (int i = 0; i < 4; ++i)
#pragma unroll
                for (int jj = 0; jj < 4; ++jj)
                    acc[i][jj] = fmaf(a[i], b[jj], acc[i][jj]);
        }
        __syncthreads();
    }

    if (mode == 1) {
#pragma unroll
        for (int i = 0; i < 4; ++i) {
            float4 vv = make_float4(acc[i][0], acc[i][1], acc[i][2], acc[i][3]);
            *(float4*)&dense[(size_t)(bm + ty * 4 + i) * N + bn + tx * 4] = vv;
        }
    } else {
        // 64-wide column tile aligned to 64 -> exactly one (which, head)
        const int which = bn / C_DIM;
        const int h     = (bn % C_DIM) / HD;
        float* dst = (which == 0) ? qo : ((which == 1) ? ko : vo);
#pragma unroll
        for (int i = 0; i < 4; ++i) {
            const int m = bm + ty * 4 + i;
            const int b = m / T_DIM, t = m % T_DIM;
            float4 vv = make_float4(acc[i][0], acc[i][1], acc[i][2], acc[i][3]);
            *(float4*)&dst[((size_t)(b * NH + h) * T_DIM + t) * HD + tx * 4] = vv;
        }
    }
}

// ---------------------------------------------------------------------------
// Flash-style causal attention, fp32.
// Q,K,V: [B*H, T, 64].  out: [B, T, C] (written at c = h*64 + d).
// Block: 256 threads = 64 q-rows x 4 d-quarters. 64-wide K/V tiles.
// Online softmax (running max m, denom l) per q-row; the 4 threads of a row
// are adjacent lanes -> shfl_xor(1|2) row reductions.
// ---------------------------------------------------------------------------
__global__ __launch_bounds__(256) void attn_fp32_kernel(
    const float* __restrict__ q, const float* __restrict__ k,
    const float* __restrict__ v, float* __restrict__ out)
{
    __shared__ float Qs[64][68];   // pad 4 -> 16B-aligned rows for float4 LDS reads
    __shared__ float Ks[64][68];
    __shared__ float Vs[64][68];
    __shared__ float Ps[64][68];

    const int bh  = blockIdx.y;
    const int bb  = bh / NH, hh = bh % NH;
    const int q0  = blockIdx.x * 64;
    const int tid = threadIdx.x;
    const int r   = tid >> 2;   // q-row within tile, 0..63
    const int j   = tid & 3;    // d-quarter / k-quarter, 0..3

    const float* Qp = q + (size_t)bh * T_DIM * HD;
    const float* Kp = k + (size_t)bh * T_DIM * HD;
    const float* Vp = v + (size_t)bh * T_DIM * HD;

#pragma unroll
    for (int i = 0; i < 4; ++i) {
        const int idx = tid + i * 256;           // 0..1023 float4 slots
        const int rr = idx >> 4, cc = (idx & 15) * 4;
        *(float4*)&Qs[rr][cc] = *(const float4*)&Qp[(size_t)(q0 + rr) * HD + cc];
    }

    const float scale = 0.125f;  // 1/sqrt(64)
    float m_run = -__builtin_inff();
    float l_run = 0.0f;
    float o[16];
#pragma unroll
    for (int c = 0; c < 16; ++c) o[c] = 0.0f;

    const int ktiles = (q0 >> 6) + 1;   // causal: only tiles with k0 <= q0
    for (int kt = 0; kt < ktiles; ++kt) {
        const int k0 = kt * 64;
        __syncthreads();   // previous iter's Vs/Ps reads done (also covers Qs on iter 0)
#pragma unroll
        for (int i = 0; i < 4; ++i) {
            const int idx = tid + i * 256;
            const int rr = idx >> 4, cc = (idx & 15) * 4;
            *(float4*)&Ks[rr][cc] = *(const float4*)&Kp[(size_t)(k0 + rr) * HD + cc];
            *(float4*)&Vs[rr][cc] = *(const float4*)&Vp[(size_t)(k0 + rr) * HD + cc];
        }
        __syncthreads();

        // scores: this thread covers S[r][j*16 .. j*16+15]
        float s[16];
#pragma unroll
        for (int c = 0; c < 16; ++c) s[c] = 0.0f;
        for (int d0 = 0; d0 < HD; d0 += 4) {
            const float4 qv = *(const float4*)&Qs[r][d0];
#pragma unroll
            for (int c = 0; c < 16; ++c) {
                const float4 kv = *(const float4*)&Ks[j * 16 + c][d0];
                s[c] += qv.x * kv.x + qv.y * kv.y + qv.z * kv.z + qv.w * kv.w;
            }
        }
        float tm = -__builtin_inff();
#pragma unroll
        for (int c = 0; c < 16; ++c) {
            s[c] *= scale;
            if (k0 + j * 16 + c > q0 + r) s[c] = -__builtin_inff();  // causal mask
            tm = fmaxf(tm, s[c]);
        }
        // row-tile max across the 4 adjacent lanes of this row
        tm = fmaxf(tm, __shfl_xor(tm, 1));
        tm = fmaxf(tm, __shfl_xor(tm, 2));
        const float m_new = fmaxf(m_run, tm);

        float p_sum = 0.0f;
#pragma unroll
        for (int c = 0; c < 16; ++c) {
            const float p = __expf(s[c] - m_new);
            Ps[r][j * 16 + c] = p;
            p_sum += p;
        }
        p_sum += __shfl_xor(p_sum, 1);
        p_sum += __shfl_xor(p_sum, 2);

        const float rescale = __expf(m_run - m_new);
        l_run = l_run * rescale + p_sum;
        m_run = m_new;
#pragma unroll
        for (int c = 0; c < 16; ++c) o[c] *= rescale;

        // PV: Ps row r is produced by this row's own 4 lanes (same wave) ->
        // DS-pipeline in-order per wave, no extra barrier needed.
        for (int kk = 0; kk < 64; ++kk) {
            const float pk = Ps[r][kk];
            const float4 v0 = *(const float4*)&Vs[kk][j * 16 + 0];
            const float4 v1 = *(const float4*)&Vs[kk][j * 16 + 4];
            const float4 v2 = *(const float4*)&Vs[kk][j * 16 + 8];
            const float4 v3 = *(const float4*)&Vs[kk][j * 16 + 12];
            o[0]  = fmaf(pk, v0.x, o[0]);  o[1]  = fmaf(pk, v0.y, o[1]);
            o[2]  = fmaf(pk, v0.z, o[2]);  o[3]  = fmaf(pk, v0.w, o[3]);
            o[4]  = fmaf(pk, v1.x, o[4]);  o[5]  = fmaf(pk, v1.y, o[5]);
            o[6]  = fmaf(pk, v1.z, o[6]);  o[7]  = fmaf(pk, v1.w, o[7]);
            o[8]  = fmaf(pk, v2.x, o[8]);  o[9]  = fmaf(pk, v2.y, o[9]);
            o[10] = fmaf(pk, v2.z, o[10]); o[11] = fmaf(pk, v2.w, o[11]);
            o[12] = fmaf(pk, v3.x, o[12]); o[13] = fmaf(pk, v3.y, o[13]);
            o[14] = fmaf(pk, v3.z, o[14]); o[15] = fmaf(pk, v3.w, o[15]);
        }
    }

    const float inv_l = 1.0f / l_run;
    float* orow = out + ((size_t)(bb * T_DIM + q0 + r)) * C_DIM + hh * HD + j * 16;
#pragma unroll
    for (int c4 = 0; c4 < 16; c4 += 4) {
        float4 ov = make_float4(o[c4] * inv_l, o[c4 + 1] * inv_l,
                                o[c4 + 2] * inv_l, o[c4 + 3] * inv_l);
        *(float4*)&orow[c4] = ov;
    }
}

// ---------------------------------------------------------------------------
extern "C" void kernel_launch(void* const* d_in, const int* in_sizes, int n_in,
                              void* d_out, int out_size, void* d_ws, size_t ws_size,
                              hipStream_t stream) {
    const float* x      = (const float*)d_in[0];   // [B,T,C]
    const float* W_attn = (const float*)d_in[1];   // [3C, C]
    const float* W_proj = (const float*)d_in[2];   // [C, C]
    float* out = (float*)d_out;                    // [B,T,C]

    const size_t nQ = (size_t)B_DIM * NH * T_DIM * HD;  // 3,145,728 floats
    float* qw = (float*)d_ws;
    float* kw = qw + nQ;
    float* vw = kw + nQ;
    float* aw = vw + nQ;   // attention output in [B,T,C]

    // QKV projection: M=4096, N=2304
    gemm_bt_kernel<<<dim3(2304 / 64, (B_DIM * T_DIM) / 64), 256, 0, stream>>>(
        x, W_attn, 3 * C_DIM, qw, kw, vw, nullptr, 0);

    // Causal attention: grid (T/64, B*H)
    attn_fp32_kernel<<<dim3(T_DIM / 64, B_DIM * NH), 256, 0, stream>>>(
        qw, kw, vw, aw);

    // Output projection: M=4096, N=768
    gemm_bt_kernel<<<dim3(C_DIM / 64, (B_DIM * T_DIM) / 64), 256, 0, stream>>>(
        aw, W_proj, C_DIM, nullptr, nullptr, nullptr, out, 1);
}

// Round 2
// 238.456 us; speedup vs baseline: 7.5352x; 7.5352x over previous
//
#include <hip/hip_runtime.h>

#define T_DIM 2048
#define C_DIM 768
#define NH    12
#define HD    64
#define KDIM  768

typedef __attribute__((ext_vector_type(8))) short short8;
typedef __attribute__((ext_vector_type(4))) float f32x4;
typedef unsigned short u16;

__device__ __forceinline__ u16 f2bf(float f) {
    unsigned int u = __builtin_bit_cast(unsigned int, f);
    u = (u + 0x7fffu + ((u >> 16) & 1u)) >> 16;   // RNE
    return (u16)u;
}

// ---------------------------------------------------------------------------
// fp32 -> bf16 conversion of x, W_attn, W_proj (one grid-stride kernel)
// ---------------------------------------------------------------------------
#define NX  (4096 * 768)
#define NWA (2304 * 768)
#define NWP (768 * 768)
#define TOT4 ((NX + NWA + NWP) / 4)

__global__ __launch_bounds__(256) void convert_kernel(
    const float* __restrict__ x, const float* __restrict__ wa,
    const float* __restrict__ wp, u16* __restrict__ xb,
    u16* __restrict__ wab, u16* __restrict__ wpb)
{
    for (int i4 = blockIdx.x * 256 + threadIdx.x; i4 < TOT4; i4 += gridDim.x * 256) {
        int i = i4 * 4;
        const float* src; u16* dst; int off;
        if (i < NX)            { src = x;  dst = xb;  off = i; }
        else if (i < NX + NWA) { src = wa; dst = wab; off = i - NX; }
        else                   { src = wp; dst = wpb; off = i - NX - NWA; }
        float4 v = *(const float4*)&src[off];
        ushort4 o;
        o.x = f2bf(v.x); o.y = f2bf(v.y); o.z = f2bf(v.z); o.w = f2bf(v.w);
        *(ushort4*)&dst[off] = o;
    }
}

// ---------------------------------------------------------------------------
// bf16 MFMA GEMM: out[m][n] = sum_k A[m][k] * W[n][k]   (A:[M,768], W:[N,768])
// 128x128 tile, BK=32, 256 threads = 4 waves (2x2 of 64x64), 4x4 MFMA frags.
// mode 0: scatter to q[BH,T,64], k[BH,T,64], vT[BH,64,T] (bf16)
// mode 1: dense fp32 out [M,768]
// ---------------------------------------------------------------------------
__global__ __launch_bounds__(256) void gemm_mfma(
    const u16* __restrict__ A, const u16* __restrict__ Wt, int mode,
    u16* __restrict__ qb, u16* __restrict__ kb, u16* __restrict__ vtb,
    float* __restrict__ dense)
{
    __shared__ __align__(16) u16 As[128][40];   // pad to 40 -> conflict-free b128
    __shared__ __align__(16) u16 Bs[128][40];

    const int tid = threadIdx.x;
    const int bm = blockIdx.y * 128, bn = blockIdx.x * 128;
    const int w = tid >> 6, l = tid & 63;
    const int wr = (w >> 1) * 64, wc = (w & 1) * 64;
    const int lrow = l & 15, lg = l >> 4;

    const int srow = tid >> 2;          // staging row 0..63
    const int scol = (tid & 3) * 8;     // staging col offset (bf16)

    f32x4 acc[4][4];
    const f32x4 zero4 = {0.f, 0.f, 0.f, 0.f};
#pragma unroll
    for (int mi = 0; mi < 4; ++mi)
#pragma unroll
        for (int ni = 0; ni < 4; ++ni) acc[mi][ni] = zero4;

    // prologue: stage regs for k0 = 0
    uint4 ra0 = *(const uint4*)&A [(size_t)(bm + srow)      * KDIM + scol];
    uint4 ra1 = *(const uint4*)&A [(size_t)(bm + 64 + srow) * KDIM + scol];
    uint4 rb0 = *(const uint4*)&Wt[(size_t)(bn + srow)      * KDIM + scol];
    uint4 rb1 = *(const uint4*)&Wt[(size_t)(bn + 64 + srow) * KDIM + scol];

    for (int k0 = 0; k0 < KDIM; k0 += 32) {
        __syncthreads();    // previous iter's frag reads complete
        *(uint4*)&As[srow][scol]      = ra0;
        *(uint4*)&As[64 + srow][scol] = ra1;
        *(uint4*)&Bs[srow][scol]      = rb0;
        *(uint4*)&Bs[64 + srow][scol] = rb1;
        __syncthreads();

        if (k0 + 32 < KDIM) {   // prefetch next tile into regs (hides under MFMA)
            ra0 = *(const uint4*)&A [(size_t)(bm + srow)      * KDIM + k0 + 32 + scol];
            ra1 = *(const uint4*)&A [(size_t)(bm + 64 + srow) * KDIM + k0 + 32 + scol];
            rb0 = *(const uint4*)&Wt[(size_t)(bn + srow)      * KDIM + k0 + 32 + scol];
            rb1 = *(const uint4*)&Wt[(size_t)(bn + 64 + srow) * KDIM + k0 + 32 + scol];
        }

        short8 af[4], bf[4];
#pragma unroll
        for (int mi = 0; mi < 4; ++mi)
            af[mi] = *(const short8*)&As[wr + mi * 16 + lrow][lg * 8];
#pragma unroll
        for (int ni = 0; ni < 4; ++ni)
            bf[ni] = *(const short8*)&Bs[wc + ni * 16 + lrow][lg * 8];
#pragma unroll
        for (int mi = 0; mi < 4; ++mi)
#pragma unroll
            for (int ni = 0; ni < 4; ++ni)
                acc[mi][ni] = __builtin_amdgcn_mfma_f32_16x16x32_bf16(
                    af[mi], bf[ni], acc[mi][ni], 0, 0, 0);
    }

    if (mode == 1) {
#pragma unroll
        for (int ni = 0; ni < 4; ++ni) {
            const int col = bn + wc + ni * 16 + lrow;
#pragma unroll
            for (int mi = 0; mi < 4; ++mi) {
                const int m0 = bm + wr + mi * 16 + lg * 4;
#pragma unroll
                for (int jj = 0; jj < 4; ++jj)
                    dense[(size_t)(m0 + jj) * C_DIM + col] = acc[mi][ni][jj];
            }
        }
    } else {
#pragma unroll
        for (int ni = 0; ni < 4; ++ni) {
            const int colbase = bn + wc + ni * 16;
            const int which = colbase / C_DIM;
            const int h = (colbase % C_DIM) / HD;
            const int d = (colbase % HD) + lrow;
#pragma unroll
            for (int mi = 0; mi < 4; ++mi) {
                const int t0 = bm + wr + mi * 16 + lg * 4;
                const int bb2 = t0 >> 11, tt = t0 & 2047;
                const size_t bhoff = (size_t)(bb2 * NH + h);
                if (which == 2) {
                    ushort4 pv;
                    pv.x = f2bf(acc[mi][ni][0]); pv.y = f2bf(acc[mi][ni][1]);
                    pv.z = f2bf(acc[mi][ni][2]); pv.w = f2bf(acc[mi][ni][3]);
                    *(ushort4*)&vtb[(bhoff * HD + d) * T_DIM + tt] = pv;
                } else {
                    u16* dst = (which == 0) ? qb : kb;
#pragma unroll
                    for (int jj = 0; jj < 4; ++jj)
                        dst[(bhoff * T_DIM + tt + jj) * HD + d] = f2bf(acc[mi][ni][jj]);
                }
            }
        }
    }
}

// ---------------------------------------------------------------------------
// Flash attention, bf16 MFMA. q,k: [BH,2048,64]; vT: [BH,64,2048]; out bf16
// [4096,768]. 4 independent waves/block, 16 q-rows each, KBLK=64.
// No block-wide barriers in the k-loop.
// ---------------------------------------------------------------------------
__global__ __launch_bounds__(256) void attn_mfma(
    const u16* __restrict__ q, const u16* __restrict__ k,
    const u16* __restrict__ vt, u16* __restrict__ aw)
{
    __shared__ __align__(16) u16 Ps[4][16][72];   // per-wave P bounce, padded

    const int bh = blockIdx.y, bb = bh / NH, hh = bh % NH;
    const int qt = gridDim.x - 1 - blockIdx.x;   // big tiles launch first
    const int tid = threadIdx.x, w = tid >> 6, l = tid & 63;
    const int lrow = l & 15, lg = l >> 4;
    const int qbase = qt * 64 + w * 16;

    const u16* Qp = q  + (size_t)bh * T_DIM * HD;
    const u16* Kp = k  + (size_t)bh * T_DIM * HD;
    const u16* Vp = vt + (size_t)bh * HD * T_DIM;

    short8 aq0 = *(const short8*)&Qp[(size_t)(qbase + lrow) * HD + lg * 8];
    short8 aq1 = *(const short8*)&Qp[(size_t)(qbase + lrow) * HD + 32 + lg * 8];

    const f32x4 zero4 = {0.f, 0.f, 0.f, 0.f};
    f32x4 o[4];
#pragma unroll
    for (int n = 0; n < 4; ++n) o[n] = zero4;
    float m_run[4], l_run[4];
#pragma unroll
    for (int jj = 0; jj < 4; ++jj) { m_run[jj] = -__builtin_inff(); l_run[jj] = 0.f; }

    const int nkt = qt + 1;
    for (int kt = 0; kt < nkt; ++kt) {
        const int kk0 = kt * 64;

        // ---- S = Q K^T (16 x 64), C/D layout: row=lg*4+jj, col=n*16+lrow
        f32x4 s[4];
#pragma unroll
        for (int n = 0; n < 4; ++n) {
            short8 bk0 = *(const short8*)&Kp[(size_t)(kk0 + n * 16 + lrow) * HD + lg * 8];
            short8 bk1 = *(const short8*)&Kp[(size_t)(kk0 + n * 16 + lrow) * HD + 32 + lg * 8];
            s[n] = __builtin_amdgcn_mfma_f32_16x16x32_bf16(aq0, bk0, zero4, 0, 0, 0);
            s[n] = __builtin_amdgcn_mfma_f32_16x16x32_bf16(aq1, bk1, s[n], 0, 0, 0);
        }

        const bool diag = (kt == nkt - 1);
        float p[4][4];
        float alpha[4];
#pragma unroll
        for (int jj = 0; jj < 4; ++jj) {
            float r0, r1, r2, r3;
            r0 = s[0][jj] * 0.125f; r1 = s[1][jj] * 0.125f;
            r2 = s[2][jj] * 0.125f; r3 = s[3][jj] * 0.125f;
            if (diag) {
                const int qrow = qbase + lg * 4 + jj;
                if (kk0 + 0 * 16 + lrow > qrow) r0 = -__builtin_inff();
                if (kk0 + 1 * 16 + lrow > qrow) r1 = -__builtin_inff();
                if (kk0 + 2 * 16 + lrow > qrow) r2 = -__builtin_inff();
                if (kk0 + 3 * 16 + lrow > qrow) r3 = -__builtin_inff();
            }
            p[0][jj] = r0; p[1][jj] = r1; p[2][jj] = r2; p[3][jj] = r3;
            float rm = fmaxf(fmaxf(r0, r1), fmaxf(r2, r3));
            rm = fmaxf(rm, __shfl_xor(rm, 1));
            rm = fmaxf(rm, __shfl_xor(rm, 2));
            rm = fmaxf(rm, __shfl_xor(rm, 4));
            rm = fmaxf(rm, __shfl_xor(rm, 8));
            const float mnew = fmaxf(m_run[jj], rm);
            alpha[jj] = __expf(m_run[jj] - mnew);
            m_run[jj] = mnew;
        }
#pragma unroll
        for (int n = 0; n < 4; ++n)
#pragma unroll
            for (int jj = 0; jj < 4; ++jj)
                p[n][jj] = __expf(p[n][jj] - m_run[jj]);
#pragma unroll
        for (int jj = 0; jj < 4; ++jj) {
            float rs = p[0][jj] + p[1][jj] + p[2][jj] + p[3][jj];
            rs += __shfl_xor(rs, 1);
            rs += __shfl_xor(rs, 2);
            rs += __shfl_xor(rs, 4);
            rs += __shfl_xor(rs, 8);
            l_run[jj] = l_run[jj] * alpha[jj] + rs;
            o[0][jj] *= alpha[jj]; o[1][jj] *= alpha[jj];
            o[2][jj] *= alpha[jj]; o[3][jj] *= alpha[jj];
        }

        // ---- P (C/D layout) -> LDS [16 rows][64 keys] bf16, paired b32 writes
#pragma unroll
        for (int jj = 0; jj < 4; ++jj) {
            const int row = lg * 4 + jj;
#pragma unroll
            for (int n = 0; n < 4; ++n) {
                const float po = __shfl_xor(p[n][jj], 1);
                const bool mine = ((l & 1) == 0) ? (n < 2) : (n >= 2);
                if (mine) {
                    unsigned int pk = ((l & 1) == 0)
                        ? ((unsigned int)f2bf(p[n][jj]) | ((unsigned int)f2bf(po) << 16))
                        : ((unsigned int)f2bf(po) | ((unsigned int)f2bf(p[n][jj]) << 16));
                    const int colp = (n * 16 + lrow) & ~1;
                    *(unsigned int*)&Ps[w][row][colp] = pk;
                }
            }
        }
        // same-wave LDS write->read: compiler emits lgkmcnt wait

        short8 ap0 = *(const short8*)&Ps[w][lrow][lg * 8];
        short8 ap1 = *(const short8*)&Ps[w][lrow][32 + lg * 8];

        // ---- O += P V  (B-frag contiguous from vT)
#pragma unroll
        for (int n = 0; n < 4; ++n) {
            short8 bv0 = *(const short8*)&Vp[(size_t)(n * 16 + lrow) * T_DIM + kk0 + lg * 8];
            short8 bv1 = *(const short8*)&Vp[(size_t)(n * 16 + lrow) * T_DIM + kk0 + 32 + lg * 8];
            o[n] = __builtin_amdgcn_mfma_f32_16x16x32_bf16(ap0, bv0, o[n], 0, 0, 0);
            o[n] = __builtin_amdgcn_mfma_f32_16x16x32_bf16(ap1, bv1, o[n], 0, 0, 0);
        }
    }

    float inv[4];
#pragma unroll
    for (int jj = 0; jj < 4; ++jj) inv[jj] = 1.0f / l_run[jj];
#pragma unroll
    for (int n = 0; n < 4; ++n) {
        const int col = hh * HD + n * 16 + lrow;
#pragma unroll
        for (int jj = 0; jj < 4; ++jj) {
            const int m = bb * T_DIM + qbase + lg * 4 + jj;
            aw[(size_t)m * C_DIM + col] = f2bf(o[n][jj] * inv[jj]);
        }
    }
}

// ---------------------------------------------------------------------------
extern "C" void kernel_launch(void* const* d_in, const int* in_sizes, int n_in,
                              void* d_out, int out_size, void* d_ws, size_t ws_size,
                              hipStream_t stream) {
    const float* x      = (const float*)d_in[0];
    const float* W_attn = (const float*)d_in[1];
    const float* W_proj = (const float*)d_in[2];
    float* out = (float*)d_out;

    char* ws = (char*)d_ws;
    u16* xb  = (u16*)ws;                       ws += (size_t)NX * 2;
    u16* wab = (u16*)ws;                       ws += (size_t)NWA * 2;
    u16* wpb = (u16*)ws;                       ws += (size_t)NWP * 2;
    u16* qb  = (u16*)ws;                       ws += (size_t)24 * T_DIM * HD * 2;
    u16* kb  = (u16*)ws;                       ws += (size_t)24 * T_DIM * HD * 2;
    u16* vtb = (u16*)ws;                       ws += (size_t)24 * T_DIM * HD * 2;
    u16* awb = (u16*)ws;

    convert_kernel<<<2048, 256, 0, stream>>>(x, W_attn, W_proj, xb, wab, wpb);

    // QKV: M=4096, N=2304
    gemm_mfma<<<dim3(2304 / 128, 4096 / 128), 256, 0, stream>>>(
        xb, wab, 0, qb, kb, vtb, nullptr);

    attn_mfma<<<dim3(T_DIM / 64, 24), 256, 0, stream>>>(qb, kb, vtb, awb);

    // proj: M=4096, N=768, fp32 out
    gemm_mfma<<<dim3(768 / 128, 4096 / 128), 256, 0, stream>>>(
        awb, wpb, 1, nullptr, nullptr, nullptr, out);
}

// Round 3
// 180.294 us; speedup vs baseline: 9.9660x; 1.3226x over previous
//
#include <hip/hip_runtime.h>

#define T_DIM 2048
#define C_DIM 768
#define NH    12
#define HD    64
#define KDIM  768

typedef __attribute__((ext_vector_type(8))) short short8;
typedef __attribute__((ext_vector_type(4))) float f32x4;
typedef unsigned short u16;

__device__ __forceinline__ u16 f2bf(float f) {
    unsigned int u = __builtin_bit_cast(unsigned int, f);
    u = (u + 0x7fffu + ((u >> 16) & 1u)) >> 16;   // RNE
    return (u16)u;
}
__device__ __forceinline__ f32x4 max4(f32x4 a, f32x4 b) {
    f32x4 r; r[0]=fmaxf(a[0],b[0]); r[1]=fmaxf(a[1],b[1]);
    r[2]=fmaxf(a[2],b[2]); r[3]=fmaxf(a[3],b[3]); return r;
}

// ---------------------------------------------------------------------------
// fp32 -> bf16 conversion of x, W_attn, W_proj
// ---------------------------------------------------------------------------
#define NX  (4096 * 768)
#define NWA (2304 * 768)
#define NWP (768 * 768)
#define TOT4 ((NX + NWA + NWP) / 4)

__global__ __launch_bounds__(256) void convert_kernel(
    const float* __restrict__ x, const float* __restrict__ wa,
    const float* __restrict__ wp, u16* __restrict__ xb,
    u16* __restrict__ wab, u16* __restrict__ wpb)
{
    for (int i4 = blockIdx.x * 256 + threadIdx.x; i4 < TOT4; i4 += gridDim.x * 256) {
        int i = i4 * 4;
        const float* src; u16* dst; int off;
        if (i < NX)            { src = x;  dst = xb;  off = i; }
        else if (i < NX + NWA) { src = wa; dst = wab; off = i - NX; }
        else                   { src = wp; dst = wpb; off = i - NX - NWA; }
        float4 v = *(const float4*)&src[off];
        ushort4 o;
        o.x = f2bf(v.x); o.y = f2bf(v.y); o.z = f2bf(v.z); o.w = f2bf(v.w);
        *(ushort4*)&dst[off] = o;
    }
}

// ---------------------------------------------------------------------------
// bf16 MFMA GEMM (see R2). mode 0 scatter epilogue now folds softmax scale
// 1/8 into Q (exact bf16 exponent shift done in f32 acc).
// ---------------------------------------------------------------------------
__global__ __launch_bounds__(256) void gemm_mfma(
    const u16* __restrict__ A, const u16* __restrict__ Wt, int mode,
    u16* __restrict__ qb, u16* __restrict__ kb, u16* __restrict__ vtb,
    float* __restrict__ dense)
{
    __shared__ __align__(16) u16 As[128][40];
    __shared__ __align__(16) u16 Bs[128][40];

    const int tid = threadIdx.x;
    const int bm = blockIdx.y * 128, bn = blockIdx.x * 128;
    const int w = tid >> 6, l = tid & 63;
    const int wr = (w >> 1) * 64, wc = (w & 1) * 64;
    const int lrow = l & 15, lg = l >> 4;

    const int srow = tid >> 2;
    const int scol = (tid & 3) * 8;

    f32x4 acc[4][4];
    const f32x4 zero4 = {0.f, 0.f, 0.f, 0.f};
#pragma unroll
    for (int mi = 0; mi < 4; ++mi)
#pragma unroll
        for (int ni = 0; ni < 4; ++ni) acc[mi][ni] = zero4;

    uint4 ra0 = *(const uint4*)&A [(size_t)(bm + srow)      * KDIM + scol];
    uint4 ra1 = *(const uint4*)&A [(size_t)(bm + 64 + srow) * KDIM + scol];
    uint4 rb0 = *(const uint4*)&Wt[(size_t)(bn + srow)      * KDIM + scol];
    uint4 rb1 = *(const uint4*)&Wt[(size_t)(bn + 64 + srow) * KDIM + scol];

    for (int k0 = 0; k0 < KDIM; k0 += 32) {
        __syncthreads();
        *(uint4*)&As[srow][scol]      = ra0;
        *(uint4*)&As[64 + srow][scol] = ra1;
        *(uint4*)&Bs[srow][scol]      = rb0;
        *(uint4*)&Bs[64 + srow][scol] = rb1;
        __syncthreads();

        if (k0 + 32 < KDIM) {
            ra0 = *(const uint4*)&A [(size_t)(bm + srow)      * KDIM + k0 + 32 + scol];
            ra1 = *(const uint4*)&A [(size_t)(bm + 64 + srow) * KDIM + k0 + 32 + scol];
            rb0 = *(const uint4*)&Wt[(size_t)(bn + srow)      * KDIM + k0 + 32 + scol];
            rb1 = *(const uint4*)&Wt[(size_t)(bn + 64 + srow) * KDIM + k0 + 32 + scol];
        }

        short8 af[4], bf[4];
#pragma unroll
        for (int mi = 0; mi < 4; ++mi)
            af[mi] = *(const short8*)&As[wr + mi * 16 + lrow][lg * 8];
#pragma unroll
        for (int ni = 0; ni < 4; ++ni)
            bf[ni] = *(const short8*)&Bs[wc + ni * 16 + lrow][lg * 8];
#pragma unroll
        for (int mi = 0; mi < 4; ++mi)
#pragma unroll
            for (int ni = 0; ni < 4; ++ni)
                acc[mi][ni] = __builtin_amdgcn_mfma_f32_16x16x32_bf16(
                    af[mi], bf[ni], acc[mi][ni], 0, 0, 0);
    }

    if (mode == 1) {
#pragma unroll
        for (int ni = 0; ni < 4; ++ni) {
            const int col = bn + wc + ni * 16 + lrow;
#pragma unroll
            for (int mi = 0; mi < 4; ++mi) {
                const int m0 = bm + wr + mi * 16 + lg * 4;
#pragma unroll
                for (int jj = 0; jj < 4; ++jj)
                    dense[(size_t)(m0 + jj) * C_DIM + col] = acc[mi][ni][jj];
            }
        }
    } else {
#pragma unroll
        for (int ni = 0; ni < 4; ++ni) {
            const int colbase = bn + wc + ni * 16;
            const int which = colbase / C_DIM;
            const int h = (colbase % C_DIM) / HD;
            const int d = (colbase % HD) + lrow;
            const float qs = (which == 0) ? 0.125f : 1.0f;  // fold 1/sqrt(64) into Q
#pragma unroll
            for (int mi = 0; mi < 4; ++mi) {
                const int t0 = bm + wr + mi * 16 + lg * 4;
                const int bb2 = t0 >> 11, tt = t0 & 2047;
                const size_t bhoff = (size_t)(bb2 * NH + h);
                if (which == 2) {
                    ushort4 pv;
                    pv.x = f2bf(acc[mi][ni][0]); pv.y = f2bf(acc[mi][ni][1]);
                    pv.z = f2bf(acc[mi][ni][2]); pv.w = f2bf(acc[mi][ni][3]);
                    *(ushort4*)&vtb[(bhoff * HD + d) * T_DIM + tt] = pv;
                } else {
                    u16* dst = (which == 0) ? qb : kb;
#pragma unroll
                    for (int jj = 0; jj < 4; ++jj)
                        dst[(bhoff * T_DIM + tt + jj) * HD + d] = f2bf(acc[mi][ni][jj] * qs);
                }
            }
        }
    }
}

// ---------------------------------------------------------------------------
// Flash attention, swapped-QK^T bf16 MFMA.
// q (pre-scaled by 1/8), k: [BH,2048,64]; vT: [BH,64,2048]; out aw bf16 [4096,768].
// Block: 256 thr = 4 waves, each wave owns 16 q-rows (qbase = qt*64+w*16).
// KVBLK=128, K & V^T tiles staged once per block in padded LDS (reg-prefetch).
// S^T = mfma(K,Q): lane holds P[k(32 vals)][q=lane&15] -> in-register row
// reduction (tree) + shfl_xor(16/32) only. P -> per-wave LDS (cvt_pk) -> PV.
// ---------------------------------------------------------------------------
__global__ __launch_bounds__(256) void attn_mfma(
    const u16* __restrict__ q, const u16* __restrict__ k,
    const u16* __restrict__ vt, u16* __restrict__ aw)
{
    __shared__ __align__(16) u16 Ks [128][72];    // K[t_local][d]
    __shared__ __align__(16) u16 Vts[64][136];    // V^T[d][t_local]
    __shared__ __align__(16) u16 Ps [4][16][136]; // per-wave P[q_local][k_local]

    const int bh = blockIdx.y, bb = bh / NH, hh = bh % NH;
    const int qt = gridDim.x - 1 - blockIdx.x;    // big tiles first
    const int tid = threadIdx.x, w = tid >> 6, l = tid & 63;
    const int lrow = l & 15, lg = l >> 4;
    const int qbase = qt * 64 + w * 16;

    const u16* Qp = q  + (size_t)bh * T_DIM * HD;
    const u16* Kp = k  + (size_t)bh * T_DIM * HD;
    const u16* Vp = vt + (size_t)bh * HD * T_DIM;

    const short8 aq0 = *(const short8*)&Qp[(size_t)(qbase + lrow) * HD + lg * 8];
    const short8 aq1 = *(const short8*)&Qp[(size_t)(qbase + lrow) * HD + 32 + lg * 8];

    const f32x4 zero4 = {0.f, 0.f, 0.f, 0.f};
    f32x4 o[4];
#pragma unroll
    for (int n = 0; n < 4; ++n) o[n] = zero4;
    float m_run = -3.0e38f;   // per-lane, q = qbase + lrow
    float l_run = 0.0f;

    const int nkt = qt / 2 + 1;   // ceil((qt*64+64)/128); uniform across waves

    uint4 ka[4], va[4];
#pragma unroll
    for (int t = 0; t < 4; ++t) {
        ka[t] = *(const uint4*)&Kp[(size_t)(t * 32 + (tid >> 3)) * HD + (tid & 7) * 8];
        va[t] = *(const uint4*)&Vp[(size_t)(t * 16 + (tid >> 4)) * T_DIM + (tid & 15) * 8];
    }

    for (int kt = 0; kt < nkt; ++kt) {
        const int kk0 = kt * 128;
        __syncthreads();   // prior iter's Ks/Vts reads complete
#pragma unroll
        for (int t = 0; t < 4; ++t) {
            *(uint4*)&Ks [t * 32 + (tid >> 3)][(tid & 7) * 8]  = ka[t];
            *(uint4*)&Vts[t * 16 + (tid >> 4)][(tid & 15) * 8] = va[t];
        }
        __syncthreads();

        if (kt + 1 < nkt) {   // prefetch next tile (hides under compute)
            const int nk0 = kk0 + 128;
#pragma unroll
            for (int t = 0; t < 4; ++t) {
                ka[t] = *(const uint4*)&Kp[(size_t)(nk0 + t * 32 + (tid >> 3)) * HD + (tid & 7) * 8];
                va[t] = *(const uint4*)&Vp[(size_t)(t * 16 + (tid >> 4)) * T_DIM + nk0 + (tid & 15) * 8];
            }
        }

        // ---- S^T = K Q^T : s[n][jj] = S[k = kk0+n*16+lg*4+jj][q = qbase+lrow]
        f32x4 s[8];
#pragma unroll
        for (int n = 0; n < 8; ++n) {
            const short8 kf0 = *(const short8*)&Ks[n * 16 + lrow][lg * 8];
            const short8 kf1 = *(const short8*)&Ks[n * 16 + lrow][32 + lg * 8];
            s[n] = __builtin_amdgcn_mfma_f32_16x16x32_bf16(kf0, aq0, zero4, 0, 0, 0);
            s[n] = __builtin_amdgcn_mfma_f32_16x16x32_bf16(kf1, aq1, s[n], 0, 0, 0);
        }

        if (kt == nkt - 1) {   // only the last tile can cross the diagonal
            const int qg = qbase + lrow;
#pragma unroll
            for (int n = 0; n < 8; ++n)
#pragma unroll
                for (int jj = 0; jj < 4; ++jj)
                    if (kk0 + n * 16 + lg * 4 + jj > qg) s[n][jj] = -3.0e38f;
        }

        // ---- per-lane max over 32 values (tree), then 2 shuffles
        f32x4 t0 = max4(max4(s[0], s[1]), max4(s[2], s[3]));
        f32x4 t1 = max4(max4(s[4], s[5]), max4(s[6], s[7]));
        f32x4 t2 = max4(t0, t1);
        float rm = fmaxf(fmaxf(t2[0], t2[1]), fmaxf(t2[2], t2[3]));
        rm = fmaxf(rm, __shfl_xor(rm, 16));
        rm = fmaxf(rm, __shfl_xor(rm, 32));
        const float m_new = fmaxf(m_run, rm);
        const float alpha = __expf(m_run - m_new);
        m_run = m_new;

        // ---- p = exp(s - m), in place; sum tree
#pragma unroll
        for (int n = 0; n < 8; ++n)
#pragma unroll
            for (int jj = 0; jj < 4; ++jj)
                s[n][jj] = __expf(s[n][jj] - m_new);

        f32x4 a0 = (s[0] + s[1]) + (s[2] + s[3]);
        f32x4 a1 = (s[4] + s[5]) + (s[6] + s[7]);
        f32x4 a2 = a0 + a1;
        float rs = (a2[0] + a2[1]) + (a2[2] + a2[3]);
        rs += __shfl_xor(rs, 16);
        rs += __shfl_xor(rs, 32);
        l_run = l_run * alpha + rs;

        // ---- P -> LDS bf16 (k is lane-local: no shuffles needed)
#pragma unroll
        for (int n = 0; n < 8; ++n) {
            unsigned int r0, r1;
            asm("v_cvt_pk_bf16_f32 %0, %1, %2" : "=v"(r0) : "v"(s[n][0]), "v"(s[n][1]));
            asm("v_cvt_pk_bf16_f32 %0, %1, %2" : "=v"(r1) : "v"(s[n][2]), "v"(s[n][3]));
            uint2 pr; pr.x = r0; pr.y = r1;
            *(uint2*)&Ps[w][lrow][n * 16 + lg * 4] = pr;
        }

        // ---- rescale O by alpha (broadcast to o-layout rows q = lg*4+jj)
#pragma unroll
        for (int jj = 0; jj < 4; ++jj) {
            const float aj = __shfl(alpha, lg * 4 + jj);
            o[0][jj] *= aj; o[1][jj] *= aj; o[2][jj] *= aj; o[3][jj] *= aj;
        }

        // ---- O += P V   (A = P[q][k] from Ps, B = V^T[d][k] from Vts)
        short8 ap[4];
#pragma unroll
        for (int ks = 0; ks < 4; ++ks)
            ap[ks] = *(const short8*)&Ps[w][lrow][ks * 32 + lg * 8];
#pragma unroll
        for (int n = 0; n < 4; ++n) {
#pragma unroll
            for (int ks = 0; ks < 4; ++ks) {
                const short8 bv = *(const short8*)&Vts[n * 16 + lrow][ks * 32 + lg * 8];
                o[n] = __builtin_amdgcn_mfma_f32_16x16x32_bf16(ap[ks], bv, o[n], 0, 0, 0);
            }
        }
    }

    // ---- epilogue: normalize, write bf16 [B*T, C]
#pragma unroll
    for (int jj = 0; jj < 4; ++jj) {
        const float lj = __shfl(l_run, lg * 4 + jj);
        const float inv = 1.0f / lj;
        const size_t m = (size_t)bb * T_DIM + qbase + lg * 4 + jj;
#pragma unroll
        for (int n = 0; n < 4; ++n)
            aw[m * C_DIM + hh * HD + n * 16 + lrow] = f2bf(o[n][jj] * inv);
    }
}

// ---------------------------------------------------------------------------
extern "C" void kernel_launch(void* const* d_in, const int* in_sizes, int n_in,
                              void* d_out, int out_size, void* d_ws, size_t ws_size,
                              hipStream_t stream) {
    const float* x      = (const float*)d_in[0];
    const float* W_attn = (const float*)d_in[1];
    const float* W_proj = (const float*)d_in[2];
    float* out = (float*)d_out;

    char* ws = (char*)d_ws;
    u16* xb  = (u16*)ws;                       ws += (size_t)NX * 2;
    u16* wab = (u16*)ws;                       ws += (size_t)NWA * 2;
    u16* wpb = (u16*)ws;                       ws += (size_t)NWP * 2;
    u16* qb  = (u16*)ws;                       ws += (size_t)24 * T_DIM * HD * 2;
    u16* kb  = (u16*)ws;                       ws += (size_t)24 * T_DIM * HD * 2;
    u16* vtb = (u16*)ws;                       ws += (size_t)24 * T_DIM * HD * 2;
    u16* awb = (u16*)ws;

    convert_kernel<<<2048, 256, 0, stream>>>(x, W_attn, W_proj, xb, wab, wpb);

    gemm_mfma<<<dim3(2304 / 128, 4096 / 128), 256, 0, stream>>>(
        xb, wab, 0, qb, kb, vtb, nullptr);

    attn_mfma<<<dim3(T_DIM / 64, 24), 256, 0, stream>>>(qb, kb, vtb, awb);

    gemm_mfma<<<dim3(768 / 128, 4096 / 128), 256, 0, stream>>>(
        awb, wpb, 1, nullptr, nullptr, nullptr, out);
}

// Round 4
// 178.706 us; speedup vs baseline: 10.0545x; 1.0089x over previous
//
#include <hip/hip_runtime.h>

#define T_DIM 2048
#define C_DIM 768
#define NH    12
#define HD    64
#define KDIM  768

typedef __attribute__((ext_vector_type(8))) short short8;
typedef __attribute__((ext_vector_type(4))) float f32x4;
typedef unsigned short u16;

__device__ __forceinline__ u16 f2bf(float f) {
    unsigned int u = __builtin_bit_cast(unsigned int, f);
    u = (u + 0x7fffu + ((u >> 16) & 1u)) >> 16;   // RNE
    return (u16)u;
}
__device__ __forceinline__ f32x4 max4(f32x4 a, f32x4 b) {
    f32x4 r; r[0]=fmaxf(a[0],b[0]); r[1]=fmaxf(a[1],b[1]);
    r[2]=fmaxf(a[2],b[2]); r[3]=fmaxf(a[3],b[3]); return r;
}

// ---------------------------------------------------------------------------
// fp32 -> bf16 conversion of x, W_attn, W_proj
// ---------------------------------------------------------------------------
#define NX  (4096 * 768)
#define NWA (2304 * 768)
#define NWP (768 * 768)
#define TOT4 ((NX + NWA + NWP) / 4)

__global__ __launch_bounds__(256) void convert_kernel(
    const float* __restrict__ x, const float* __restrict__ wa,
    const float* __restrict__ wp, u16* __restrict__ xb,
    u16* __restrict__ wab, u16* __restrict__ wpb)
{
    for (int i4 = blockIdx.x * 256 + threadIdx.x; i4 < TOT4; i4 += gridDim.x * 256) {
        int i = i4 * 4;
        const float* src; u16* dst; int off;
        if (i < NX)            { src = x;  dst = xb;  off = i; }
        else if (i < NX + NWA) { src = wa; dst = wab; off = i - NX; }
        else                   { src = wp; dst = wpb; off = i - NX - NWA; }
        float4 v = *(const float4*)&src[off];
        ushort4 o;
        o.x = f2bf(v.x); o.y = f2bf(v.y); o.z = f2bf(v.z); o.w = f2bf(v.w);
        *(ushort4*)&dst[off] = o;
    }
}

// ---------------------------------------------------------------------------
// bf16 MFMA GEMM. mode 0: scatter to q/k/vT (folds softmax 1/8 into Q).
// mode 1: dense fp32 out.
// ---------------------------------------------------------------------------
__global__ __launch_bounds__(256) void gemm_mfma(
    const u16* __restrict__ A, const u16* __restrict__ Wt, int mode,
    u16* __restrict__ qb, u16* __restrict__ kb, u16* __restrict__ vtb,
    float* __restrict__ dense)
{
    __shared__ __align__(16) u16 As[128][40];
    __shared__ __align__(16) u16 Bs[128][40];

    const int tid = threadIdx.x;
    const int bm = blockIdx.y * 128, bn = blockIdx.x * 128;
    const int w = tid >> 6, l = tid & 63;
    const int wr = (w >> 1) * 64, wc = (w & 1) * 64;
    const int lrow = l & 15, lg = l >> 4;

    const int srow = tid >> 2;
    const int scol = (tid & 3) * 8;

    f32x4 acc[4][4];
    const f32x4 zero4 = {0.f, 0.f, 0.f, 0.f};
#pragma unroll
    for (int mi = 0; mi < 4; ++mi)
#pragma unroll
        for (int ni = 0; ni < 4; ++ni) acc[mi][ni] = zero4;

    uint4 ra0 = *(const uint4*)&A [(size_t)(bm + srow)      * KDIM + scol];
    uint4 ra1 = *(const uint4*)&A [(size_t)(bm + 64 + srow) * KDIM + scol];
    uint4 rb0 = *(const uint4*)&Wt[(size_t)(bn + srow)      * KDIM + scol];
    uint4 rb1 = *(const uint4*)&Wt[(size_t)(bn + 64 + srow) * KDIM + scol];

    for (int k0 = 0; k0 < KDIM; k0 += 32) {
        __syncthreads();
        *(uint4*)&As[srow][scol]      = ra0;
        *(uint4*)&As[64 + srow][scol] = ra1;
        *(uint4*)&Bs[srow][scol]      = rb0;
        *(uint4*)&Bs[64 + srow][scol] = rb1;
        __syncthreads();

        if (k0 + 32 < KDIM) {
            ra0 = *(const uint4*)&A [(size_t)(bm + srow)      * KDIM + k0 + 32 + scol];
            ra1 = *(const uint4*)&A [(size_t)(bm + 64 + srow) * KDIM + k0 + 32 + scol];
            rb0 = *(const uint4*)&Wt[(size_t)(bn + srow)      * KDIM + k0 + 32 + scol];
            rb1 = *(const uint4*)&Wt[(size_t)(bn + 64 + srow) * KDIM + k0 + 32 + scol];
        }

        short8 af[4], bf[4];
#pragma unroll
        for (int mi = 0; mi < 4; ++mi)
            af[mi] = *(const short8*)&As[wr + mi * 16 + lrow][lg * 8];
#pragma unroll
        for (int ni = 0; ni < 4; ++ni)
            bf[ni] = *(const short8*)&Bs[wc + ni * 16 + lrow][lg * 8];
#pragma unroll
        for (int mi = 0; mi < 4; ++mi)
#pragma unroll
            for (int ni = 0; ni < 4; ++ni)
                acc[mi][ni] = __builtin_amdgcn_mfma_f32_16x16x32_bf16(
                    af[mi], bf[ni], acc[mi][ni], 0, 0, 0);
    }

    if (mode == 1) {
#pragma unroll
        for (int ni = 0; ni < 4; ++ni) {
            const int col = bn + wc + ni * 16 + lrow;
#pragma unroll
            for (int mi = 0; mi < 4; ++mi) {
                const int m0 = bm + wr + mi * 16 + lg * 4;
#pragma unroll
                for (int jj = 0; jj < 4; ++jj)
                    dense[(size_t)(m0 + jj) * C_DIM + col] = acc[mi][ni][jj];
            }
        }
    } else {
#pragma unroll
        for (int ni = 0; ni < 4; ++ni) {
            const int colbase = bn + wc + ni * 16;
            const int which = colbase / C_DIM;
            const int h = (colbase % C_DIM) / HD;
            const int d = (colbase % HD) + lrow;
            const float qs = (which == 0) ? 0.125f : 1.0f;  // fold 1/sqrt(64) into Q
#pragma unroll
            for (int mi = 0; mi < 4; ++mi) {
                const int t0 = bm + wr + mi * 16 + lg * 4;
                const int bb2 = t0 >> 11, tt = t0 & 2047;
                const size_t bhoff = (size_t)(bb2 * NH + h);
                if (which == 2) {
                    ushort4 pv;
                    pv.x = f2bf(acc[mi][ni][0]); pv.y = f2bf(acc[mi][ni][1]);
                    pv.z = f2bf(acc[mi][ni][2]); pv.w = f2bf(acc[mi][ni][3]);
                    *(ushort4*)&vtb[(bhoff * HD + d) * T_DIM + tt] = pv;
                } else {
                    u16* dst = (which == 0) ? qb : kb;
#pragma unroll
                    for (int jj = 0; jj < 4; ++jj)
                        dst[(bhoff * T_DIM + tt + jj) * HD + d] = f2bf(acc[mi][ni][jj] * qs);
                }
            }
        }
    }
}

// ---------------------------------------------------------------------------
// Flash attention, swapped-QK^T bf16 MFMA.
// __launch_bounds__(256, 2): min 2 waves/EU -> VGPR cap 256. R3's default
// heuristic capped at 72 VGPRs and spilled ~130-reg live set to scratch
// (WRITE_SIZE 133 MB vs 6 MB of real output). Live set ~130 fits w/o spill.
// ---------------------------------------------------------------------------
__global__ __launch_bounds__(256, 2) void attn_mfma(
    const u16* __restrict__ q, const u16* __restrict__ k,
    const u16* __restrict__ vt, u16* __restrict__ aw)
{
    __shared__ __align__(16) u16 Ks [128][72];    // K[t_local][d]
    __shared__ __align__(16) u16 Vts[64][136];    // V^T[d][t_local]
    __shared__ __align__(16) u16 Ps [4][16][136]; // per-wave P[q_local][k_local]

    const int bh = blockIdx.y, bb = bh / NH, hh = bh % NH;
    const int qt = gridDim.x - 1 - blockIdx.x;    // big tiles first
    const int tid = threadIdx.x, w = tid >> 6, l = tid & 63;
    const int lrow = l & 15, lg = l >> 4;
    const int qbase = qt * 64 + w * 16;

    const u16* Qp = q  + (size_t)bh * T_DIM * HD;
    const u16* Kp = k  + (size_t)bh * T_DIM * HD;
    const u16* Vp = vt + (size_t)bh * HD * T_DIM;

    const short8 aq0 = *(const short8*)&Qp[(size_t)(qbase + lrow) * HD + lg * 8];
    const short8 aq1 = *(const short8*)&Qp[(size_t)(qbase + lrow) * HD + 32 + lg * 8];

    const f32x4 zero4 = {0.f, 0.f, 0.f, 0.f};
    f32x4 o[4];
#pragma unroll
    for (int n = 0; n < 4; ++n) o[n] = zero4;
    float m_run = -3.0e38f;   // per-lane, q = qbase + lrow
    float l_run = 0.0f;

    const int nkt = qt / 2 + 1;   // ceil((qt*64+64)/128); uniform across waves

    uint4 ka[4], va[4];
#pragma unroll
    for (int t = 0; t < 4; ++t) {
        ka[t] = *(const uint4*)&Kp[(size_t)(t * 32 + (tid >> 3)) * HD + (tid & 7) * 8];
        va[t] = *(const uint4*)&Vp[(size_t)(t * 16 + (tid >> 4)) * T_DIM + (tid & 15) * 8];
    }

    for (int kt = 0; kt < nkt; ++kt) {
        const int kk0 = kt * 128;
        __syncthreads();   // prior iter's Ks/Vts reads complete
#pragma unroll
        for (int t = 0; t < 4; ++t) {
            *(uint4*)&Ks [t * 32 + (tid >> 3)][(tid & 7) * 8]  = ka[t];
            *(uint4*)&Vts[t * 16 + (tid >> 4)][(tid & 15) * 8] = va[t];
        }
        __syncthreads();

        if (kt + 1 < nkt) {   // prefetch next tile (hides under compute)
            const int nk0 = kk0 + 128;
#pragma unroll
            for (int t = 0; t < 4; ++t) {
                ka[t] = *(const uint4*)&Kp[(size_t)(nk0 + t * 32 + (tid >> 3)) * HD + (tid & 7) * 8];
                va[t] = *(const uint4*)&Vp[(size_t)(t * 16 + (tid >> 4)) * T_DIM + nk0 + (tid & 15) * 8];
            }
        }

        // ---- S^T = K Q^T : s[n][jj] = S[k = kk0+n*16+lg*4+jj][q = qbase+lrow]
        f32x4 s[8];
#pragma unroll
        for (int n = 0; n < 8; ++n) {
            const short8 kf0 = *(const short8*)&Ks[n * 16 + lrow][lg * 8];
            const short8 kf1 = *(const short8*)&Ks[n * 16 + lrow][32 + lg * 8];
            s[n] = __builtin_amdgcn_mfma_f32_16x16x32_bf16(kf0, aq0, zero4, 0, 0, 0);
            s[n] = __builtin_amdgcn_mfma_f32_16x16x32_bf16(kf1, aq1, s[n], 0, 0, 0);
        }

        if (kt == nkt - 1) {   // only the last tile can cross the diagonal
            const int qg = qbase + lrow;
#pragma unroll
            for (int n = 0; n < 8; ++n)
#pragma unroll
                for (int jj = 0; jj < 4; ++jj)
                    if (kk0 + n * 16 + lg * 4 + jj > qg) s[n][jj] = -3.0e38f;
        }

        // ---- per-lane max over 32 values (tree), then 2 shuffles
        f32x4 t0 = max4(max4(s[0], s[1]), max4(s[2], s[3]));
        f32x4 t1 = max4(max4(s[4], s[5]), max4(s[6], s[7]));
        f32x4 t2 = max4(t0, t1);
        float rm = fmaxf(fmaxf(t2[0], t2[1]), fmaxf(t2[2], t2[3]));
        rm = fmaxf(rm, __shfl_xor(rm, 16));
        rm = fmaxf(rm, __shfl_xor(rm, 32));
        const float m_new = fmaxf(m_run, rm);
        const float alpha = __expf(m_run - m_new);
        m_run = m_new;

        // ---- p = exp(s - m), in place; sum tree
#pragma unroll
        for (int n = 0; n < 8; ++n)
#pragma unroll
            for (int jj = 0; jj < 4; ++jj)
                s[n][jj] = __expf(s[n][jj] - m_new);

        f32x4 a0 = (s[0] + s[1]) + (s[2] + s[3]);
        f32x4 a1 = (s[4] + s[5]) + (s[6] + s[7]);
        f32x4 a2 = a0 + a1;
        float rs = (a2[0] + a2[1]) + (a2[2] + a2[3]);
        rs += __shfl_xor(rs, 16);
        rs += __shfl_xor(rs, 32);
        l_run = l_run * alpha + rs;

        // ---- P -> LDS bf16 (k is lane-local: no shuffles needed)
#pragma unroll
        for (int n = 0; n < 8; ++n) {
            unsigned int r0, r1;
            asm("v_cvt_pk_bf16_f32 %0, %1, %2" : "=v"(r0) : "v"(s[n][0]), "v"(s[n][1]));
            asm("v_cvt_pk_bf16_f32 %0, %1, %2" : "=v"(r1) : "v"(s[n][2]), "v"(s[n][3]));
            uint2 pr; pr.x = r0; pr.y = r1;
            *(uint2*)&Ps[w][lrow][n * 16 + lg * 4] = pr;
        }

        // ---- rescale O by alpha (broadcast to o-layout rows q = lg*4+jj)
#pragma unroll
        for (int jj = 0; jj < 4; ++jj) {
            const float aj = __shfl(alpha, lg * 4 + jj);
            o[0][jj] *= aj; o[1][jj] *= aj; o[2][jj] *= aj; o[3][jj] *= aj;
        }

        // ---- O += P V   (A = P[q][k] from Ps, B = V^T[d][k] from Vts)
        short8 ap[4];
#pragma unroll
        for (int ks = 0; ks < 4; ++ks)
            ap[ks] = *(const short8*)&Ps[w][lrow][ks * 32 + lg * 8];
#pragma unroll
        for (int n = 0; n < 4; ++n) {
#pragma unroll
            for (int ks = 0; ks < 4; ++ks) {
                const short8 bv = *(const short8*)&Vts[n * 16 + lrow][ks * 32 + lg * 8];
                o[n] = __builtin_amdgcn_mfma_f32_16x16x32_bf16(ap[ks], bv, o[n], 0, 0, 0);
            }
        }
    }

    // ---- epilogue: normalize, write bf16 [B*T, C]
#pragma unroll
    for (int jj = 0; jj < 4; ++jj) {
        const float lj = __shfl(l_run, lg * 4 + jj);
        const float inv = 1.0f / lj;
        const size_t m = (size_t)bb * T_DIM + qbase + lg * 4 + jj;
#pragma unroll
        for (int n = 0; n < 4; ++n)
            aw[m * C_DIM + hh * HD + n * 16 + lrow] = f2bf(o[n][jj] * inv);
    }
}

// ---------------------------------------------------------------------------
extern "C" void kernel_launch(void* const* d_in, const int* in_sizes, int n_in,
                              void* d_out, int out_size, void* d_ws, size_t ws_size,
                              hipStream_t stream) {
    const float* x      = (const float*)d_in[0];
    const float* W_attn = (const float*)d_in[1];
    const float* W_proj = (const float*)d_in[2];
    float* out = (float*)d_out;

    char* ws = (char*)d_ws;
    u16* xb  = (u16*)ws;                       ws += (size_t)NX * 2;
    u16* wab = (u16*)ws;                       ws += (size_t)NWA * 2;
    u16* wpb = (u16*)ws;                       ws += (size_t)NWP * 2;
    u16* qb  = (u16*)ws;                       ws += (size_t)24 * T_DIM * HD * 2;
    u16* kb  = (u16*)ws;                       ws += (size_t)24 * T_DIM * HD * 2;
    u16* vtb = (u16*)ws;                       ws += (size_t)24 * T_DIM * HD * 2;
    u16* awb = (u16*)ws;

    convert_kernel<<<2048, 256, 0, stream>>>(x, W_attn, W_proj, xb, wab, wpb);

    gemm_mfma<<<dim3(2304 / 128, 4096 / 128), 256, 0, stream>>>(
        xb, wab, 0, qb, kb, vtb, nullptr);

    attn_mfma<<<dim3(T_DIM / 64, 24), 256, 0, stream>>>(qb, kb, vtb, awb);

    gemm_mfma<<<dim3(768 / 128, 4096 / 128), 256, 0, stream>>>(
        awb, wpb, 1, nullptr, nullptr, nullptr, out);
}

// Round 5
// 110.680 us; speedup vs baseline: 16.2342x; 1.6146x over previous
//
#include <hip/hip_runtime.h>

#define T_DIM 2048
#define C_DIM 768
#define NH    12
#define HD    64
#define KDIM  768
#define NJOBS (24 * 32)

typedef __attribute__((ext_vector_type(8))) short short8;
typedef __attribute__((ext_vector_type(4))) float f32x4;
typedef unsigned short u16;

__device__ __forceinline__ u16 f2bf(float f) {
    unsigned int u = __builtin_bit_cast(unsigned int, f);
    u = (u + 0x7fffu + ((u >> 16) & 1u)) >> 16;   // RNE
    return (u16)u;
}
__device__ __forceinline__ f32x4 max4(f32x4 a, f32x4 b) {
    f32x4 r; r[0]=fmaxf(a[0],b[0]); r[1]=fmaxf(a[1],b[1]);
    r[2]=fmaxf(a[2],b[2]); r[3]=fmaxf(a[3],b[3]); return r;
}

// ---------------------------------------------------------------------------
// fp32 -> bf16 conversion of x, W_attn, W_proj (+ zeroes the attn job counter)
// ---------------------------------------------------------------------------
#define NX  (4096 * 768)
#define NWA (2304 * 768)
#define NWP (768 * 768)
#define TOT4 ((NX + NWA + NWP) / 4)

__global__ __launch_bounds__(256) void convert_kernel(
    const float* __restrict__ x, const float* __restrict__ wa,
    const float* __restrict__ wp, u16* __restrict__ xb,
    u16* __restrict__ wab, u16* __restrict__ wpb, int* __restrict__ counter)
{
    if (blockIdx.x == 0 && threadIdx.x == 0) *counter = 0;
    for (int i4 = blockIdx.x * 256 + threadIdx.x; i4 < TOT4; i4 += gridDim.x * 256) {
        int i = i4 * 4;
        const float* src; u16* dst; int off;
        if (i < NX)            { src = x;  dst = xb;  off = i; }
        else if (i < NX + NWA) { src = wa; dst = wab; off = i - NX; }
        else                   { src = wp; dst = wpb; off = i - NX - NWA; }
        float4 v = *(const float4*)&src[off];
        ushort4 o;
        o.x = f2bf(v.x); o.y = f2bf(v.y); o.z = f2bf(v.z); o.w = f2bf(v.w);
        *(ushort4*)&dst[off] = o;
    }
}

// ---------------------------------------------------------------------------
// bf16 MFMA GEMM. mode 0: scatter to q/k/vT (folds softmax 1/8 into Q).
// mode 1: dense fp32 out.
// ---------------------------------------------------------------------------
__global__ __launch_bounds__(256) void gemm_mfma(
    const u16* __restrict__ A, const u16* __restrict__ Wt, int mode,
    u16* __restrict__ qb, u16* __restrict__ kb, u16* __restrict__ vtb,
    float* __restrict__ dense)
{
    __shared__ __align__(16) u16 As[128][40];
    __shared__ __align__(16) u16 Bs[128][40];

    const int tid = threadIdx.x;
    const int bm = blockIdx.y * 128, bn = blockIdx.x * 128;
    const int w = tid >> 6, l = tid & 63;
    const int wr = (w >> 1) * 64, wc = (w & 1) * 64;
    const int lrow = l & 15, lg = l >> 4;

    const int srow = tid >> 2;
    const int scol = (tid & 3) * 8;

    f32x4 acc[4][4];
    const f32x4 zero4 = {0.f, 0.f, 0.f, 0.f};
#pragma unroll
    for (int mi = 0; mi < 4; ++mi)
#pragma unroll
        for (int ni = 0; ni < 4; ++ni) acc[mi][ni] = zero4;

    uint4 ra0 = *(const uint4*)&A [(size_t)(bm + srow)      * KDIM + scol];
    uint4 ra1 = *(const uint4*)&A [(size_t)(bm + 64 + srow) * KDIM + scol];
    uint4 rb0 = *(const uint4*)&Wt[(size_t)(bn + srow)      * KDIM + scol];
    uint4 rb1 = *(const uint4*)&Wt[(size_t)(bn + 64 + srow) * KDIM + scol];

    for (int k0 = 0; k0 < KDIM; k0 += 32) {
        __syncthreads();
        *(uint4*)&As[srow][scol]      = ra0;
        *(uint4*)&As[64 + srow][scol] = ra1;
        *(uint4*)&Bs[srow][scol]      = rb0;
        *(uint4*)&Bs[64 + srow][scol] = rb1;
        __syncthreads();

        if (k0 + 32 < KDIM) {
            ra0 = *(const uint4*)&A [(size_t)(bm + srow)      * KDIM + k0 + 32 + scol];
            ra1 = *(const uint4*)&A [(size_t)(bm + 64 + srow) * KDIM + k0 + 32 + scol];
            rb0 = *(const uint4*)&Wt[(size_t)(bn + srow)      * KDIM + k0 + 32 + scol];
            rb1 = *(const uint4*)&Wt[(size_t)(bn + 64 + srow) * KDIM + k0 + 32 + scol];
        }

        short8 af[4], bf[4];
#pragma unroll
        for (int mi = 0; mi < 4; ++mi)
            af[mi] = *(const short8*)&As[wr + mi * 16 + lrow][lg * 8];
#pragma unroll
        for (int ni = 0; ni < 4; ++ni)
            bf[ni] = *(const short8*)&Bs[wc + ni * 16 + lrow][lg * 8];
#pragma unroll
        for (int mi = 0; mi < 4; ++mi)
#pragma unroll
            for (int ni = 0; ni < 4; ++ni)
                acc[mi][ni] = __builtin_amdgcn_mfma_f32_16x16x32_bf16(
                    af[mi], bf[ni], acc[mi][ni], 0, 0, 0);
    }

    if (mode == 1) {
#pragma unroll
        for (int ni = 0; ni < 4; ++ni) {
            const int col = bn + wc + ni * 16 + lrow;
#pragma unroll
            for (int mi = 0; mi < 4; ++mi) {
                const int m0 = bm + wr + mi * 16 + lg * 4;
#pragma unroll
                for (int jj = 0; jj < 4; ++jj)
                    dense[(size_t)(m0 + jj) * C_DIM + col] = acc[mi][ni][jj];
            }
        }
    } else {
#pragma unroll
        for (int ni = 0; ni < 4; ++ni) {
            const int colbase = bn + wc + ni * 16;
            const int which = colbase / C_DIM;
            const int h = (colbase % C_DIM) / HD;
            const int d = (colbase % HD) + lrow;
            const float qs = (which == 0) ? 0.125f : 1.0f;  // fold 1/sqrt(64) into Q
#pragma unroll
            for (int mi = 0; mi < 4; ++mi) {
                const int t0 = bm + wr + mi * 16 + lg * 4;
                const int bb2 = t0 >> 11, tt = t0 & 2047;
                const size_t bhoff = (size_t)(bb2 * NH + h);
                if (which == 2) {
                    ushort4 pv;
                    pv.x = f2bf(acc[mi][ni][0]); pv.y = f2bf(acc[mi][ni][1]);
                    pv.z = f2bf(acc[mi][ni][2]); pv.w = f2bf(acc[mi][ni][3]);
                    *(ushort4*)&vtb[(bhoff * HD + d) * T_DIM + tt] = pv;
                } else {
                    u16* dst = (which == 0) ? qb : kb;
#pragma unroll
                    for (int jj = 0; jj < 4; ++jj)
                        dst[(bhoff * T_DIM + tt + jj) * HD + d] = f2bf(acc[mi][ni][jj] * qs);
                }
            }
        }
    }
}

// ---------------------------------------------------------------------------
// Flash attention, swapped-QK^T bf16 MFMA — persistent-block work-queue form.
// Jobs = (bh, q-tile) issued big-first via atomicAdd (LPT balance).
// Per job: stage K/V 128-key tiles in LDS (transient regs, no prefetch regs),
// then two 64-key sub-blocks: s[4] scores, in-register softmax (swapped
// layout), P->LDS bounce (cvt_pk), PV MFMA. Live set ~60 VGPR -> no spill.
// ---------------------------------------------------------------------------
__global__ __launch_bounds__(256, 2) void attn_mfma(
    const u16* __restrict__ q, const u16* __restrict__ k,
    const u16* __restrict__ vt, u16* __restrict__ aw, int* __restrict__ counter)
{
    __shared__ __align__(16) u16 Ks [128][72];    // K[t_local][d]
    __shared__ __align__(16) u16 Vts[64][136];    // V^T[d][t_local]
    __shared__ __align__(16) u16 Ps [4][16][72];  // per-wave P[q_local][k_local(64)]
    __shared__ int job_s;

    const int tid = threadIdx.x, w = tid >> 6, l = tid & 63;
    const int lrow = l & 15, lg = l >> 4;
    const f32x4 zero4 = {0.f, 0.f, 0.f, 0.f};

    for (;;) {
        __syncthreads();                       // all waves done with prior job's LDS
        if (tid == 0) job_s = atomicAdd(counter, 1);
        __syncthreads();
        const int j = job_s;
        if (j >= NJOBS) break;                 // uniform exit

        const int qt = 31 - (j / 24);          // big q-tiles first (LPT)
        const int bh = j - (j / 24) * 24;
        const int bb = bh / NH, hh = bh % NH;
        const int qbase = qt * 64 + w * 16;
        const int qg = qbase + lrow;           // this lane's q row

        const u16* Qp = q  + (size_t)bh * T_DIM * HD;
        const u16* Kp = k  + (size_t)bh * T_DIM * HD;
        const u16* Vp = vt + (size_t)bh * HD * T_DIM;

        const short8 aq0 = *(const short8*)&Qp[(size_t)(qbase + lrow) * HD + lg * 8];
        const short8 aq1 = *(const short8*)&Qp[(size_t)(qbase + lrow) * HD + 32 + lg * 8];

        f32x4 o[4];
#pragma unroll
        for (int n = 0; n < 4; ++n) o[n] = zero4;
        float m_run = -3.0e38f;
        float l_run = 0.0f;

        const int nkt = qt / 2 + 1;
        for (int kt = 0; kt < nkt; ++kt) {
            const int kk0 = kt * 128;
            __syncthreads();                   // prior tile's LDS reads complete

            // ---- stage K (128x64) and V^T (64x128); transient regs only
            {
                uint4 kr[4], vr[4];
#pragma unroll
                for (int t = 0; t < 4; ++t) {
                    kr[t] = *(const uint4*)&Kp[(size_t)(kk0 + t * 32 + (tid >> 3)) * HD + (tid & 7) * 8];
                    vr[t] = *(const uint4*)&Vp[(size_t)(t * 16 + (tid >> 4)) * T_DIM + kk0 + (tid & 15) * 8];
                }
#pragma unroll
                for (int t = 0; t < 4; ++t) {
                    *(uint4*)&Ks [t * 32 + (tid >> 3)][(tid & 7) * 8]  = kr[t];
                    *(uint4*)&Vts[t * 16 + (tid >> 4)][(tid & 15) * 8] = vr[t];
                }
            }
            __syncthreads();

            const bool last = (kt == nkt - 1);
            const int nsub = (last && (qt & 1) == 0) ? 1 : 2;  // skip fully-masked half
            for (int sub = 0; sub < nsub; ++sub) {
                const int kb0 = kk0 + sub * 64;
                const bool masked = last && (sub == nsub - 1);

                // ---- S^T sub-tile: s[n][jj] = S[k=kb0+n*16+lg*4+jj][q=qg]
                f32x4 s[4];
#pragma unroll
                for (int n = 0; n < 4; ++n) {
                    const short8 kf0 = *(const short8*)&Ks[sub * 64 + n * 16 + lrow][lg * 8];
                    const short8 kf1 = *(const short8*)&Ks[sub * 64 + n * 16 + lrow][32 + lg * 8];
                    s[n] = __builtin_amdgcn_mfma_f32_16x16x32_bf16(kf0, aq0, zero4, 0, 0, 0);
                    s[n] = __builtin_amdgcn_mfma_f32_16x16x32_bf16(kf1, aq1, s[n], 0, 0, 0);
                }

                if (masked) {
#pragma unroll
                    for (int n = 0; n < 4; ++n)
#pragma unroll
                        for (int jj = 0; jj < 4; ++jj)
                            if (kb0 + n * 16 + lg * 4 + jj > qg) s[n][jj] = -3.0e38f;
                }

                // ---- online softmax (per-lane tree + 2 shuffles)
                f32x4 t2 = max4(max4(s[0], s[1]), max4(s[2], s[3]));
                float rm = fmaxf(fmaxf(t2[0], t2[1]), fmaxf(t2[2], t2[3]));
                rm = fmaxf(rm, __shfl_xor(rm, 16));
                rm = fmaxf(rm, __shfl_xor(rm, 32));
                const float m_new = fmaxf(m_run, rm);
                const float alpha = __expf(m_run - m_new);
                m_run = m_new;

#pragma unroll
                for (int n = 0; n < 4; ++n)
#pragma unroll
                    for (int jj = 0; jj < 4; ++jj)
                        s[n][jj] = __expf(s[n][jj] - m_new);

                f32x4 a2 = (s[0] + s[1]) + (s[2] + s[3]);
                float rs = (a2[0] + a2[1]) + (a2[2] + a2[3]);
                rs += __shfl_xor(rs, 16);
                rs += __shfl_xor(rs, 32);
                l_run = l_run * alpha + rs;

                // ---- P -> LDS bf16 (k lane-local: no shuffles)
#pragma unroll
                for (int n = 0; n < 4; ++n) {
                    unsigned int r0, r1;
                    asm("v_cvt_pk_bf16_f32 %0, %1, %2" : "=v"(r0) : "v"(s[n][0]), "v"(s[n][1]));
                    asm("v_cvt_pk_bf16_f32 %0, %1, %2" : "=v"(r1) : "v"(s[n][2]), "v"(s[n][3]));
                    uint2 pr; pr.x = r0; pr.y = r1;
                    *(uint2*)&Ps[w][lrow][n * 16 + lg * 4] = pr;
                }

                // ---- rescale O
#pragma unroll
                for (int jj = 0; jj < 4; ++jj) {
                    const float aj = __shfl(alpha, lg * 4 + jj);
                    o[0][jj] *= aj; o[1][jj] *= aj; o[2][jj] *= aj; o[3][jj] *= aj;
                }

                // ---- O += P V (same-wave LDS RW order guarantees Ps ready)
                const short8 ap0 = *(const short8*)&Ps[w][lrow][lg * 8];
                const short8 ap1 = *(const short8*)&Ps[w][lrow][32 + lg * 8];
#pragma unroll
                for (int n = 0; n < 4; ++n) {
                    const short8 bv0 = *(const short8*)&Vts[n * 16 + lrow][sub * 64 + lg * 8];
                    const short8 bv1 = *(const short8*)&Vts[n * 16 + lrow][sub * 64 + 32 + lg * 8];
                    o[n] = __builtin_amdgcn_mfma_f32_16x16x32_bf16(ap0, bv0, o[n], 0, 0, 0);
                    o[n] = __builtin_amdgcn_mfma_f32_16x16x32_bf16(ap1, bv1, o[n], 0, 0, 0);
                }
            }
        }

        // ---- epilogue: normalize, write bf16 [B*T, C]
#pragma unroll
        for (int jj = 0; jj < 4; ++jj) {
            const float lj = __shfl(l_run, lg * 4 + jj);
            const float inv = 1.0f / lj;
            const size_t m = (size_t)bb * T_DIM + qbase + lg * 4 + jj;
#pragma unroll
            for (int n = 0; n < 4; ++n)
                aw[m * C_DIM + hh * HD + n * 16 + lrow] = f2bf(o[n][jj] * inv);
        }
    }
}

// ---------------------------------------------------------------------------
extern "C" void kernel_launch(void* const* d_in, const int* in_sizes, int n_in,
                              void* d_out, int out_size, void* d_ws, size_t ws_size,
                              hipStream_t stream) {
    const float* x      = (const float*)d_in[0];
    const float* W_attn = (const float*)d_in[1];
    const float* W_proj = (const float*)d_in[2];
    float* out = (float*)d_out;

    char* ws = (char*)d_ws;
    u16* xb  = (u16*)ws;                       ws += (size_t)NX * 2;
    u16* wab = (u16*)ws;                       ws += (size_t)NWA * 2;
    u16* wpb = (u16*)ws;                       ws += (size_t)NWP * 2;
    u16* qb  = (u16*)ws;                       ws += (size_t)24 * T_DIM * HD * 2;
    u16* kb  = (u16*)ws;                       ws += (size_t)24 * T_DIM * HD * 2;
    u16* vtb = (u16*)ws;                       ws += (size_t)24 * T_DIM * HD * 2;
    u16* awb = (u16*)ws;                       ws += (size_t)4096 * C_DIM * 2;
    int* cnt = (int*)ws;

    convert_kernel<<<2048, 256, 0, stream>>>(x, W_attn, W_proj, xb, wab, wpb, cnt);

    gemm_mfma<<<dim3(2304 / 128, 4096 / 128), 256, 0, stream>>>(
        xb, wab, 0, qb, kb, vtb, nullptr);

    attn_mfma<<<512, 256, 0, stream>>>(qb, kb, vtb, awb, cnt);

    gemm_mfma<<<dim3(768 / 128, 4096 / 128), 256, 0, stream>>>(
        awb, wpb, 1, nullptr, nullptr, nullptr, out);
}